// Round 1
// baseline (1636.663 us; speedup 1.0000x reference)
//
#include <hip/hip_runtime.h>
#include <math.h>

#define HD 256      // hidden dim
#define TPTS 32     // points per block
#define KT 32       // k-tile for W2 staging
#define NSTEPS 100
#define TH 5e-5f

__device__ __forceinline__ float secant_pred(float sl, float sh, float zl, float zh) {
    float den = sh - sl;
    den = (fabsf(den) > 1e-12f) ? den : 1e-12f;
    return -sl * (zh - zl) / den + zl;
}

// ---------------------------------------------------------------------------
// Fused SDF eval: block of 256 threads evaluates 32 points.
// Each thread handles 2 hidden columns (j0 = tid&127, j1 = j0+128) for 16
// points (threads <128 -> points 0..15, threads >=128 -> points 16..31).
// mode: 0 = write always; 1 = write (mask ? s : 0); 2 = write only if mask.
// ---------------------------------------------------------------------------
__global__ __launch_bounds__(256, 2) void eval_kernel(
    const float* __restrict__ cam, const float* __restrict__ rays, int R,
    const float* __restrict__ tarr,                       // per-point t, or null -> linspace
    const float* __restrict__ smin, const float* __restrict__ smax,
    int spr,                                              // samples per ray
    const int* __restrict__ mask, int maskByRay, int mode,
    float* __restrict__ out, int npoints,
    const float* __restrict__ W1, const float* __restrict__ b1,
    const float* __restrict__ W2, const float* __restrict__ b2,
    const float* __restrict__ W3, const float* __restrict__ b3)
{
    __shared__ float h1[TPTS][HD];     // 32 KB
    __shared__ float w2t[KT][HD];      // 32 KB
    __shared__ float ptsS[TPTS][4];
    __shared__ int   pmaskS[TPTS];
    __shared__ float redw[4][TPTS / 2];

    const int tid  = threadIdx.x;
    const int pid0 = blockIdx.x * TPTS;

    int myMask = 0;
    if (tid < TPTS) {
        int pid = pid0 + tid;
        float px = 0.f, py = 0.f, pz = 0.f;
        int m = 0;
        if (pid < npoints) {
            int r, i;
            if (spr == 1) { r = (pid < R) ? pid : pid - R; i = 0; }
            else          { r = pid / spr; i = pid - r * spr; }
            float t;
            if (tarr) t = tarr[pid];
            else {
                float a = smin[r], bmx = smax[r];
                t = a + (bmx - a) * ((float)i / (float)(spr - 1));
            }
            m = mask ? mask[maskByRay ? r : pid] : 1;
            px = cam[3 * r + 0] + t * rays[3 * r + 0];
            py = cam[3 * r + 1] + t * rays[3 * r + 1];
            pz = cam[3 * r + 2] + t * rays[3 * r + 2];
        }
        ptsS[tid][0] = px; ptsS[tid][1] = py; ptsS[tid][2] = pz;
        pmaskS[tid] = m;
        myMask = m;
    }
    int anyActive = __syncthreads_count((tid < TPTS) ? myMask : 0);
    if (anyActive == 0) {
        // nothing to compute; mode 1 still must write zeros for masked lanes
        if (mode == 1 && tid < TPTS) {
            int pid = pid0 + tid;
            if (pid < npoints) out[pid] = 0.0f;
        }
        return;
    }

    const int half  = tid >> 7;          // 0 or 1
    const int j0    = tid & 127;
    const int j1    = j0 + 128;
    const int pbase = half * (TPTS / 2); // 0 or 16

    // ---- layer 1: h1 = tanh(p @ W1 + b1) ----
    {
        float wa0 = W1[j0], wa1 = W1[HD + j0], wa2 = W1[2 * HD + j0], ba = b1[j0];
        float wb0 = W1[j1], wb1 = W1[HD + j1], wb2 = W1[2 * HD + j1], bb = b1[j1];
#pragma unroll
        for (int i = 0; i < TPTS / 2; ++i) {
            int p = pbase + i;
            float x = ptsS[p][0], y = ptsS[p][1], z = ptsS[p][2];
            h1[p][j0] = tanhf(ba + x * wa0 + y * wa1 + z * wa2);
            h1[p][j1] = tanhf(bb + x * wb0 + y * wb1 + z * wb2);
        }
    }
    __syncthreads();

    // ---- layer 2: acc = h1 @ W2 + b2 (k-tiled through LDS) ----
    float acca[TPTS / 2], accb[TPTS / 2];
    {
        float b2a = b2[j0], b2b = b2[j1];
#pragma unroll
        for (int i = 0; i < TPTS / 2; ++i) { acca[i] = b2a; accb[i] = b2b; }
    }
    for (int k0 = 0; k0 < HD; k0 += KT) {
        for (int idx = tid; idx < KT * HD; idx += 256)
            ((float*)w2t)[idx] = W2[k0 * HD + idx];
        __syncthreads();
#pragma unroll
        for (int kk = 0; kk < KT; kk += 4) {
            float wa0 = w2t[kk][j0], wa1 = w2t[kk + 1][j0], wa2 = w2t[kk + 2][j0], wa3 = w2t[kk + 3][j0];
            float wb0 = w2t[kk][j1], wb1 = w2t[kk + 1][j1], wb2 = w2t[kk + 2][j1], wb3 = w2t[kk + 3][j1];
#pragma unroll
            for (int i = 0; i < TPTS / 2; ++i) {
                const float4 h4 = *(const float4*)&h1[pbase + i][k0 + kk];
                acca[i] = fmaf(h4.w, wa3, fmaf(h4.z, wa2, fmaf(h4.y, wa1, fmaf(h4.x, wa0, acca[i]))));
                accb[i] = fmaf(h4.w, wb3, fmaf(h4.z, wb2, fmaf(h4.y, wb1, fmaf(h4.x, wb0, accb[i]))));
            }
        }
        __syncthreads();
    }

    // ---- layer 3 + reduction: s = base + 0.05*(tanh(acc) @ W3 + b3) ----
    {
        float w3a = W3[j0], w3b = W3[j1];
        float sum[TPTS / 2];
#pragma unroll
        for (int i = 0; i < TPTS / 2; ++i)
            sum[i] = tanhf(acca[i]) * w3a + tanhf(accb[i]) * w3b;
#pragma unroll
        for (int off = 32; off > 0; off >>= 1)
#pragma unroll
            for (int i = 0; i < TPTS / 2; ++i)
                sum[i] += __shfl_down(sum[i], off);
        int wave = tid >> 6, lane = tid & 63;
        if (lane == 0)
#pragma unroll
            for (int i = 0; i < TPTS / 2; ++i) redw[wave][i] = sum[i];
    }
    __syncthreads();
    if (tid < TPTS) {
        int p = tid;
        int w0 = (p < TPTS / 2) ? 0 : 2;
        int ii = p & (TPTS / 2 - 1);
        float tot = redw[w0][ii] + redw[w0 + 1][ii];
        float x = ptsS[p][0], y = ptsS[p][1], z = ptsS[p][2];
        float base = sqrtf(x * x + y * y + z * z + 1e-12f) - 0.6f;
        float s = base + 0.05f * (tot + b3[0]);
        int pid = pid0 + p;
        if (pid < npoints) {
            if (mode == 0)      out[pid] = s;
            else if (mode == 1) out[pid] = pmaskS[p] ? s : 0.0f;
            else if (pmaskS[p]) out[pid] = s;
        }
    }
}

// ---------------------------------------------------------------------------
// per-ray elementwise kernels
// ---------------------------------------------------------------------------
__global__ void k_init(const float* __restrict__ cam, const float* __restrict__ rays,
                       float* __restrict__ acc, int* __restrict__ unfin, int R)
{
    int r = blockIdx.x * blockDim.x + threadIdx.x;
    if (r >= R) return;
    float cx = cam[3 * r], cy = cam[3 * r + 1], cz = cam[3 * r + 2];
    float dx = rays[3 * r], dy = rays[3 * r + 1], dz = rays[3 * r + 2];
    float rcd = cx * dx + cy * dy + cz * dz;
    float cc = cx * cx + cy * cy + cz * cz;
    float under = rcd * rcd - (cc - 1.0f);
    int mi = under > 0.0f;
    float sq = sqrtf(mi ? under : 1.0f);
    float a0 = mi ? fmaxf(-sq - rcd, 0.0f) : 0.0f;
    float a1 = mi ? fmaxf(sq - rcd, 0.0f) : 0.0f;
    acc[r] = a0; acc[R + r] = a1;
    unfin[r] = mi; unfin[R + r] = mi;
}

__global__ void k_step(float* __restrict__ acc, const float* __restrict__ nsdf,
                       float* __restrict__ csdf, int* __restrict__ unfin, int R, int dom)
{
    int r = blockIdx.x * blockDim.x + threadIdx.x;
    if (r >= R) return;
    float as = acc[r], ae = acc[R + r];
    int us = unfin[r], ue = unfin[R + r];
    if (dom) { int d = as < ae; us = us && d; ue = ue && d; }
    float cs = us ? nsdf[r] : 0.0f;     cs = (cs <= TH) ? 0.0f : cs;
    float ce = ue ? nsdf[R + r] : 0.0f; ce = (ce <= TH) ? 0.0f : ce;
    us = us && (cs > TH); ue = ue && (ce > TH);
    acc[r] = as + cs; acc[R + r] = ae - ce;
    csdf[r] = cs; csdf[R + r] = ce;
    unfin[r] = us; unfin[R + r] = ue;
}

__global__ void k_ls(float* __restrict__ acc, const float* __restrict__ nsdf,
                     const float* __restrict__ csdf, int* __restrict__ npmask, int R, int n2)
{
    int i = blockIdx.x * blockDim.x + threadIdx.x;
    if (i >= n2) return;
    int np = nsdf[i] < 0.0f;
    npmask[i] = np;
    if (np) {
        float sgn = (i < R) ? -1.0f : 1.0f;   // start end backs up, end end moves forward
        acc[i] += sgn * 0.5f * csdf[i];
    }
}

__global__ void k_post(const float* __restrict__ cam, const float* __restrict__ rays,
                       const float* __restrict__ acc, const float* __restrict__ nsdf,
                       const int* __restrict__ unfin, int* __restrict__ smask,
                       float* __restrict__ smin, float* __restrict__ smax,
                       float* __restrict__ out, int R)
{
    int r = blockIdx.x * blockDim.x + threadIdx.x;
    if (r >= R) return;
    float as = acc[r], ae = acc[R + r];
    int us = unfin[r];
    int d = as < ae;
    us = us && d;                               // loop-end domain check
    float cs = us ? nsdf[r] : 0.0f;
    cs = (cs <= TH) ? 0.0f : cs;
    us = us && (cs > TH);                       // final mask refinement
    smask[r] = us;
    smin[r] = us ? as : 0.0f;
    smax[r] = us ? ae : 0.0f;
    // preliminary outputs (sampler path overwrites where smask)
    out[3 * r + 0] = cam[3 * r + 0] + as * rays[3 * r + 0];
    out[3 * r + 1] = cam[3 * r + 1] + as * rays[3 * r + 1];
    out[3 * r + 2] = cam[3 * r + 2] + as * rays[3 * r + 2];
    out[3 * R + r] = d ? 1.0f : 0.0f;
    out[4 * R + r] = as;
}

__global__ void k_argmin(const float* __restrict__ sdfv, const float* __restrict__ smin,
                         const float* __restrict__ smax, const int* __restrict__ smask,
                         float* __restrict__ zlow, float* __restrict__ zhigh,
                         float* __restrict__ slow, float* __restrict__ shigh,
                         float* __restrict__ zpred, float* __restrict__ sdorig,
                         int* __restrict__ netsurf, int R)
{
    int r = blockIdx.x * blockDim.x + threadIdx.x;
    if (r >= R) return;
    float a = smin[r], b = smax[r];
    float d = b - a;
    float best = 1e30f; int ind = 0;
    for (int i = 0; i < NSTEPS; ++i) {
        float sv = sdfv[r * NSTEPS + i];
        float sgn = (float)((sv > 0.0f) - (sv < 0.0f));
        float tmp = sgn * (float)(NSTEPS - i);
        if (tmp < best) { best = tmp; ind = i; }
    }
    float zh = a + d * ((float)ind / (float)(NSTEPS - 1));
    float sh = sdfv[r * NSTEPS + ind];
    int il = (ind + NSTEPS - 1) % NSTEPS;
    float zl = a + d * ((float)il / (float)(NSTEPS - 1));
    float sl = sdfv[r * NSTEPS + il];
    int ns = (sh < 0.0f) && smask[r];
    netsurf[r] = ns;
    sdorig[r] = zh;
    zlow[r] = zl; zhigh[r] = zh; slow[r] = sl; shigh[r] = sh;
    zpred[r] = secant_pred(sl, sh, zl, zh);
}

__global__ void k_sec(const float* __restrict__ sdmid, float* __restrict__ zlow,
                      float* __restrict__ zhigh, float* __restrict__ slow,
                      float* __restrict__ shigh, float* __restrict__ zpred,
                      const int* __restrict__ smask, int R)
{
    int r = blockIdx.x * blockDim.x + threadIdx.x;
    if (r >= R) return;
    if (!smask[r]) return;
    float sm = sdmid[r];
    float zl = zlow[r], zh = zhigh[r], sl = slow[r], sh = shigh[r], zp = zpred[r];
    if (sm > 0.0f) { zl = zp; sl = sm; }
    if (sm < 0.0f) { zh = zp; sh = sm; }
    zlow[r] = zl; zhigh[r] = zh; slow[r] = sl; shigh[r] = sh;
    zpred[r] = secant_pred(sl, sh, zl, zh);
}

__global__ void k_final(const float* __restrict__ cam, const float* __restrict__ rays,
                        const int* __restrict__ smask, const int* __restrict__ netsurf,
                        const float* __restrict__ zpred, const float* __restrict__ sdorig,
                        float* __restrict__ out, int R)
{
    int r = blockIdx.x * blockDim.x + threadIdx.x;
    if (r >= R) return;
    if (!smask[r]) return;
    int ns = netsurf[r];
    float dist = ns ? zpred[r] : sdorig[r];
    out[3 * r + 0] = cam[3 * r + 0] + dist * rays[3 * r + 0];
    out[3 * r + 1] = cam[3 * r + 1] + dist * rays[3 * r + 1];
    out[3 * r + 2] = cam[3 * r + 2] + dist * rays[3 * r + 2];
    out[3 * R + r] = ns ? 1.0f : 0.0f;
    out[4 * R + r] = dist;
}

// ---------------------------------------------------------------------------
extern "C" void kernel_launch(void* const* d_in, const int* in_sizes, int n_in,
                              void* d_out, int out_size, void* d_ws, size_t ws_size,
                              hipStream_t stream)
{
    const float* cam  = (const float*)d_in[0];
    const float* rays = (const float*)d_in[1];
    const float* W1   = (const float*)d_in[3];
    const float* b1   = (const float*)d_in[4];
    const float* W2   = (const float*)d_in[5];
    const float* b2   = (const float*)d_in[6];
    const float* W3   = (const float*)d_in[7];
    const float* b3   = (const float*)d_in[8];
    const int R = in_sizes[0] / 3;
    float* out = (float*)d_out;

    float* f = (float*)d_ws;
    float* acc    = f; f += 2 * R;
    float* nsdf   = f; f += 2 * R;
    float* csdf   = f; f += 2 * R;
    float* smin   = f; f += R;
    float* smax   = f; f += R;
    float* zlow   = f; f += R;
    float* zhigh  = f; f += R;
    float* slow   = f; f += R;
    float* shigh  = f; f += R;
    float* zpred  = f; f += R;
    float* sdmid  = f; f += R;
    float* sdorig = f; f += R;
    float* sdfv   = f; f += R * NSTEPS;
    int* unfin    = (int*)f; f += 2 * R;
    int* npmask   = (int*)f; f += 2 * R;
    int* smaskA   = (int*)f; f += R;
    int* netsurf  = (int*)f; f += R;

    const int gR  = (R + 255) / 256;
    const int g2R = (2 * R + 255) / 256;

    auto evalLaunch = [&](int npoints, const float* tarr, const float* smn, const float* smx,
                          int spr, const int* mask, int maskByRay, int mode, float* o) {
        int blocks = (npoints + TPTS - 1) / TPTS;
        hipLaunchKernelGGL(eval_kernel, dim3(blocks), dim3(256), 0, stream,
                           cam, rays, R, tarr, smn, smx, spr, mask, maskByRay, mode,
                           o, npoints, W1, b1, W2, b2, W3, b3);
    };

    k_init<<<gR, 256, 0, stream>>>(cam, rays, acc, unfin, R);
    evalLaunch(2 * R, acc, nullptr, nullptr, 1, unfin, 0, 1, nsdf);

    for (int it = 0; it < 10; ++it) {
        k_step<<<gR, 256, 0, stream>>>(acc, nsdf, csdf, unfin, R, it > 0);
        evalLaunch(2 * R, acc, nullptr, nullptr, 1, unfin, 0, 1, nsdf);
        k_ls<<<g2R, 256, 0, stream>>>(acc, nsdf, csdf, npmask, R, 2 * R);
        evalLaunch(2 * R, acc, nullptr, nullptr, 1, npmask, 0, 2, nsdf);
    }

    k_post<<<gR, 256, 0, stream>>>(cam, rays, acc, nsdf, unfin, smaskA, smin, smax, out, R);
    evalLaunch(R * NSTEPS, nullptr, smin, smax, NSTEPS, smaskA, 1, 2, sdfv);
    k_argmin<<<gR, 256, 0, stream>>>(sdfv, smin, smax, smaskA, zlow, zhigh, slow, shigh,
                                     zpred, sdorig, netsurf, R);
    for (int i = 0; i < 8; ++i) {
        evalLaunch(R, zpred, nullptr, nullptr, 1, smaskA, 1, 2, sdmid);
        k_sec<<<gR, 256, 0, stream>>>(sdmid, zlow, zhigh, slow, shigh, zpred, smaskA, R);
    }
    k_final<<<gR, 256, 0, stream>>>(cam, rays, smaskA, netsurf, zpred, sdorig, out, R);
}

// Round 3
// 1515.778 us; speedup vs baseline: 1.0798x; 1.0798x over previous
//
#include <hip/hip_runtime.h>
#include <math.h>

#define HD 256      // hidden dim
#define TPTS 32     // points per block
#define KT 32       // k-tile for W2 staging
#define NSTEPS 100
#define TH 5e-5f

__device__ __forceinline__ float secant_pred(float sl, float sh, float zl, float zh) {
    float den = sh - sl;
    den = (fabsf(den) > 1e-12f) ? den : 1e-12f;
    return -sl * (zh - zl) / den + zl;
}

// ---------------------------------------------------------------------------
// Fused SDF eval over a compacted active list.
//  sampler=0: block handles 32 list entries; entry = point id p in [0,2R);
//             ray r = p % R (p<R start end, else end end); t = tarr[p].
//  sampler=1: virtual points v in [0, cnt*NSTEPS); ray = list[v/NSTEPS],
//             step = v%NSTEPS, t = linspace(smin[r], smax[r]); out index r*NSTEPS+step.
//  doLS: epilogue performs the line-search update (np = s<0) and appends np
//        points to listB/cntB.
//  doSec: epilogue performs the secant bracket update in-place (no out write).
// ---------------------------------------------------------------------------
__global__ __launch_bounds__(256, 2) void eval_kernel(
    const float* __restrict__ cam, const float* __restrict__ rays, int R,
    const int* __restrict__ list, const int* __restrict__ cnt, int sampler,
    const float* __restrict__ tarr,
    const float* __restrict__ smin, const float* __restrict__ smax,
    float* __restrict__ out,
    int doLS, float* __restrict__ accLS, const float* __restrict__ csdf,
    int* __restrict__ listB, int* __restrict__ cntB,
    int doSec, float* __restrict__ zlow, float* __restrict__ zhigh,
    float* __restrict__ slow, float* __restrict__ shigh, float* __restrict__ zpred,
    const float* __restrict__ W1, const float* __restrict__ b1,
    const float* __restrict__ W2, const float* __restrict__ b2,
    const float* __restrict__ W3, const float* __restrict__ b3)
{
    __shared__ float h1[TPTS][HD];     // 32 KB
    __shared__ float w2t[KT][HD];      // 32 KB
    __shared__ float ptsS[TPTS][4];
    __shared__ int   pidS[TPTS];
    __shared__ float redw[4][TPTS / 2];

    const int tid = threadIdx.x;
    const int v0  = blockIdx.x * TPTS;
    const int n   = cnt[0];
    const int tot = sampler ? n * NSTEPS : n;
    if (v0 >= tot) return;   // block-uniform: no barrier reached by a subset

    if (tid < TPTS) {
        int v = v0 + tid;
        int pid = -1;
        float px = 0.f, py = 0.f, pz = 0.f;
        if (v < tot) {
            int r;
            float t;
            if (sampler) {
                int li = v / NSTEPS;
                int st = v - li * NSTEPS;
                r = list[li];
                float a = smin[r], b = smax[r];
                t = a + (b - a) * ((float)st / (float)(NSTEPS - 1));
                pid = r * NSTEPS + st;
            } else {
                int p = list[v];
                r = (p < R) ? p : p - R;
                t = tarr[p];
                pid = p;
            }
            px = cam[3 * r + 0] + t * rays[3 * r + 0];
            py = cam[3 * r + 1] + t * rays[3 * r + 1];
            pz = cam[3 * r + 2] + t * rays[3 * r + 2];
        }
        ptsS[tid][0] = px; ptsS[tid][1] = py; ptsS[tid][2] = pz;
        pidS[tid] = pid;
    }
    __syncthreads();

    const int half  = tid >> 7;          // 0 or 1
    const int j0    = tid & 127;
    const int j1    = j0 + 128;
    const int pbase = half * (TPTS / 2); // 0 or 16

    // ---- layer 1: h1 = tanh(p @ W1 + b1) ----
    {
        float wa0 = W1[j0], wa1 = W1[HD + j0], wa2 = W1[2 * HD + j0], ba = b1[j0];
        float wb0 = W1[j1], wb1 = W1[HD + j1], wb2 = W1[2 * HD + j1], bb = b1[j1];
#pragma unroll
        for (int i = 0; i < TPTS / 2; ++i) {
            int p = pbase + i;
            float x = ptsS[p][0], y = ptsS[p][1], z = ptsS[p][2];
            h1[p][j0] = tanhf(ba + x * wa0 + y * wa1 + z * wa2);
            h1[p][j1] = tanhf(bb + x * wb0 + y * wb1 + z * wb2);
        }
    }
    __syncthreads();

    // ---- layer 2: acc = h1 @ W2 + b2 (k-tiled through LDS) ----
    float acca[TPTS / 2], accb[TPTS / 2];
    {
        float b2a = b2[j0], b2b = b2[j1];
#pragma unroll
        for (int i = 0; i < TPTS / 2; ++i) { acca[i] = b2a; accb[i] = b2b; }
    }
    for (int k0 = 0; k0 < HD; k0 += KT) {
        for (int idx = tid; idx < KT * HD; idx += 256)
            ((float*)w2t)[idx] = W2[k0 * HD + idx];
        __syncthreads();
#pragma unroll
        for (int kk = 0; kk < KT; kk += 4) {
            float wa0 = w2t[kk][j0], wa1 = w2t[kk + 1][j0], wa2 = w2t[kk + 2][j0], wa3 = w2t[kk + 3][j0];
            float wb0 = w2t[kk][j1], wb1 = w2t[kk + 1][j1], wb2 = w2t[kk + 2][j1], wb3 = w2t[kk + 3][j1];
#pragma unroll
            for (int i = 0; i < TPTS / 2; ++i) {
                const float4 h4 = *(const float4*)&h1[pbase + i][k0 + kk];
                acca[i] = fmaf(h4.w, wa3, fmaf(h4.z, wa2, fmaf(h4.y, wa1, fmaf(h4.x, wa0, acca[i]))));
                accb[i] = fmaf(h4.w, wb3, fmaf(h4.z, wb2, fmaf(h4.y, wb1, fmaf(h4.x, wb0, accb[i]))));
            }
        }
        __syncthreads();
    }

    // ---- layer 3 + reduction: s = base + 0.05*(tanh(acc) @ W3 + b3) ----
    {
        float w3a = W3[j0], w3b = W3[j1];
        float sum[TPTS / 2];
#pragma unroll
        for (int i = 0; i < TPTS / 2; ++i)
            sum[i] = tanhf(acca[i]) * w3a + tanhf(accb[i]) * w3b;
#pragma unroll
        for (int off = 32; off > 0; off >>= 1)
#pragma unroll
            for (int i = 0; i < TPTS / 2; ++i)
                sum[i] += __shfl_down(sum[i], off);
        int wave = tid >> 6, lane = tid & 63;
        if (lane == 0)
#pragma unroll
            for (int i = 0; i < TPTS / 2; ++i) redw[wave][i] = sum[i];
    }
    __syncthreads();
    if (tid < TPTS) {
        int pid = pidS[tid];
        if (pid >= 0) {
            int p = tid;
            int w0 = (p < TPTS / 2) ? 0 : 2;
            int ii = p & (TPTS / 2 - 1);
            float tot3 = redw[w0][ii] + redw[w0 + 1][ii];
            float x = ptsS[p][0], y = ptsS[p][1], z = ptsS[p][2];
            float base = sqrtf(x * x + y * y + z * z + 1e-12f) - 0.6f;
            float s = base + 0.05f * (tot3 + b3[0]);
            if (doSec) {
                int r = pid;  // secant list stores ray ids
                float zl = zlow[r], zh = zhigh[r], sl = slow[r], sh = shigh[r], zp = zpred[r];
                if (s > 0.0f) { zl = zp; sl = s; }
                if (s < 0.0f) { zh = zp; sh = s; }
                zlow[r] = zl; zhigh[r] = zh; slow[r] = sl; shigh[r] = sh;
                zpred[r] = secant_pred(sl, sh, zl, zh);
            } else {
                out[pid] = s;
                if (doLS && s < 0.0f) {
                    float sgn = (pid < R) ? -0.5f : 0.5f;   // step=(1-0.5)/2^0=0.5
                    accLS[pid] += sgn * csdf[pid];
                    int ix = atomicAdd(cntB, 1);
                    listB[ix] = pid;
                }
            }
        }
    }
}

// ---------------------------------------------------------------------------
__global__ void k_zero(int* __restrict__ c) {
    if (threadIdx.x < 32) c[threadIdx.x] = 0;
}

__global__ void k_init(const float* __restrict__ cam, const float* __restrict__ rays,
                       float* __restrict__ acc, int* __restrict__ unfin,
                       int* __restrict__ listA, int* __restrict__ cntA, int R)
{
    int r = blockIdx.x * blockDim.x + threadIdx.x;
    if (r >= R) return;
    float cx = cam[3 * r], cy = cam[3 * r + 1], cz = cam[3 * r + 2];
    float dx = rays[3 * r], dy = rays[3 * r + 1], dz = rays[3 * r + 2];
    float rcd = cx * dx + cy * dy + cz * dz;
    float cc = cx * cx + cy * cy + cz * cz;
    float under = rcd * rcd - (cc - 1.0f);
    int mi = under > 0.0f;
    float sq = sqrtf(mi ? under : 1.0f);
    float a0 = mi ? fmaxf(-sq - rcd, 0.0f) : 0.0f;
    float a1 = mi ? fmaxf(sq - rcd, 0.0f) : 0.0f;
    acc[r] = a0; acc[R + r] = a1;
    unfin[r] = mi; unfin[R + r] = mi;
    if (mi) {
        int ix = atomicAdd(cntA, 2);
        listA[ix] = r; listA[ix + 1] = R + r;
    }
}

__global__ void k_step(float* __restrict__ acc, const float* __restrict__ nsdf,
                       float* __restrict__ csdf, int* __restrict__ unfin,
                       int* __restrict__ listA, int* __restrict__ cntA, int R, int dom)
{
    int r = blockIdx.x * blockDim.x + threadIdx.x;
    if (r >= R) return;
    float as = acc[r], ae = acc[R + r];
    int us = unfin[r], ue = unfin[R + r];
    if (dom) { int d = as < ae; us = us && d; ue = ue && d; }
    float cs = us ? nsdf[r] : 0.0f;     cs = (cs <= TH) ? 0.0f : cs;
    float ce = ue ? nsdf[R + r] : 0.0f; ce = (ce <= TH) ? 0.0f : ce;
    us = us && (cs > TH); ue = ue && (ce > TH);
    acc[r] = as + cs; acc[R + r] = ae - ce;
    csdf[r] = cs; csdf[R + r] = ce;
    unfin[r] = us; unfin[R + r] = ue;
    if (us) listA[atomicAdd(cntA, 1)] = r;
    if (ue) listA[atomicAdd(cntA, 1)] = R + r;
}

__global__ void k_post(const float* __restrict__ cam, const float* __restrict__ rays,
                       const float* __restrict__ acc, const float* __restrict__ nsdf,
                       const int* __restrict__ unfin,
                       int* __restrict__ listS, int* __restrict__ cntS,
                       float* __restrict__ smin, float* __restrict__ smax,
                       float* __restrict__ out, int R)
{
    int r = blockIdx.x * blockDim.x + threadIdx.x;
    if (r >= R) return;
    float as = acc[r], ae = acc[R + r];
    int us = unfin[r];
    int d = as < ae;
    us = us && d;                               // loop-end domain check
    float cs = us ? nsdf[r] : 0.0f;
    cs = (cs <= TH) ? 0.0f : cs;
    us = us && (cs > TH);                       // final mask refinement
    smin[r] = as;
    smax[r] = ae;
    if (us) listS[atomicAdd(cntS, 1)] = r;
    // preliminary outputs (sampler path overwrites where sampler_mask)
    out[3 * r + 0] = cam[3 * r + 0] + as * rays[3 * r + 0];
    out[3 * r + 1] = cam[3 * r + 1] + as * rays[3 * r + 1];
    out[3 * r + 2] = cam[3 * r + 2] + as * rays[3 * r + 2];
    out[3 * R + r] = d ? 1.0f : 0.0f;
    out[4 * R + r] = as;
}

__global__ void k_argmin(const float* __restrict__ sdfv, const float* __restrict__ smin,
                         const float* __restrict__ smax,
                         const int* __restrict__ listS, const int* __restrict__ cntS,
                         float* __restrict__ zlow, float* __restrict__ zhigh,
                         float* __restrict__ slow, float* __restrict__ shigh,
                         float* __restrict__ zpred, float* __restrict__ sdorig,
                         int* __restrict__ netsurf, int R)
{
    int j = blockIdx.x * blockDim.x + threadIdx.x;
    if (j >= cntS[0]) return;
    int r = listS[j];
    float a = smin[r], b = smax[r];
    float d = b - a;
    float best = 1e30f; int ind = 0;
    for (int i = 0; i < NSTEPS; ++i) {
        float sv = sdfv[r * NSTEPS + i];
        float sgn = (float)((sv > 0.0f) - (sv < 0.0f));
        float tmp = sgn * (float)(NSTEPS - i);
        if (tmp < best) { best = tmp; ind = i; }
    }
    float zh = a + d * ((float)ind / (float)(NSTEPS - 1));
    float sh = sdfv[r * NSTEPS + ind];
    int il = (ind + NSTEPS - 1) % NSTEPS;
    float zl = a + d * ((float)il / (float)(NSTEPS - 1));
    float sl = sdfv[r * NSTEPS + il];
    netsurf[r] = (sh < 0.0f);
    sdorig[r] = zh;
    zlow[r] = zl; zhigh[r] = zh; slow[r] = sl; shigh[r] = sh;
    zpred[r] = secant_pred(sl, sh, zl, zh);
}

__global__ void k_final(const float* __restrict__ cam, const float* __restrict__ rays,
                        const int* __restrict__ listS, const int* __restrict__ cntS,
                        const int* __restrict__ netsurf,
                        const float* __restrict__ zpred, const float* __restrict__ sdorig,
                        float* __restrict__ out, int R)
{
    int j = blockIdx.x * blockDim.x + threadIdx.x;
    if (j >= cntS[0]) return;
    int r = listS[j];
    int ns = netsurf[r];
    float dist = ns ? zpred[r] : sdorig[r];
    out[3 * r + 0] = cam[3 * r + 0] + dist * rays[3 * r + 0];
    out[3 * r + 1] = cam[3 * r + 1] + dist * rays[3 * r + 1];
    out[3 * r + 2] = cam[3 * r + 2] + dist * rays[3 * r + 2];
    out[3 * R + r] = ns ? 1.0f : 0.0f;
    out[4 * R + r] = dist;
}

// ---------------------------------------------------------------------------
extern "C" void kernel_launch(void* const* d_in, const int* in_sizes, int n_in,
                              void* d_out, int out_size, void* d_ws, size_t ws_size,
                              hipStream_t stream)
{
    const float* cam  = (const float*)d_in[0];
    const float* rays = (const float*)d_in[1];
    const float* W1   = (const float*)d_in[3];
    const float* b1   = (const float*)d_in[4];
    const float* W2   = (const float*)d_in[5];
    const float* b2   = (const float*)d_in[6];
    const float* W3   = (const float*)d_in[7];
    const float* b3   = (const float*)d_in[8];
    const int R = in_sizes[0] / 3;
    float* out = (float*)d_out;

    float* f = (float*)d_ws;
    float* acc    = f; f += 2 * R;
    float* nsdf   = f; f += 2 * R;
    float* csdf   = f; f += 2 * R;
    float* smin   = f; f += R;
    float* smax   = f; f += R;
    float* zlow   = f; f += R;
    float* zhigh  = f; f += R;
    float* slow   = f; f += R;
    float* shigh  = f; f += R;
    float* zpred  = f; f += R;
    float* sdorig = f; f += R;
    float* sdfv   = f; f += R * NSTEPS;
    int* unfin    = (int*)f; f += 2 * R;
    int* listA    = (int*)f; f += 2 * R;
    int* listB    = (int*)f; f += 2 * R;
    int* listS    = (int*)f; f += R;
    int* netsurf  = (int*)f; f += R;
    int* cnt      = (int*)f; f += 32;
    // counter slots: 0=init listA; 1+it = k_step listA; 11+it = listB; 21 = listS

    const int gR = (R + 255) / 256;
    const int gA = (2 * R + TPTS - 1) / TPTS;        // 256 blocks
    const int gS = (R * NSTEPS + TPTS - 1) / TPTS;   // 12800 blocks
    const int gC = (R + TPTS - 1) / TPTS;            // 128 blocks

    auto evalL = [&](int blocks, const int* list, const int* c, int sampler,
                     const float* tarr, float* o,
                     int doLS, int* lB, int* cB,
                     int doSec) {
        hipLaunchKernelGGL(eval_kernel, dim3(blocks), dim3(256), 0, stream,
                           cam, rays, R, list, c, sampler, tarr, smin, smax, o,
                           doLS, acc, csdf, lB, cB,
                           doSec, zlow, zhigh, slow, shigh, zpred,
                           W1, b1, W2, b2, W3, b3);
    };

    k_zero<<<1, 64, 0, stream>>>(cnt);
    k_init<<<gR, 256, 0, stream>>>(cam, rays, acc, unfin, listA, cnt + 0, R);
    evalL(gA, listA, cnt + 0, 0, acc, nsdf, 0, nullptr, nullptr, 0);

    for (int it = 0; it < 10; ++it) {
        k_step<<<gR, 256, 0, stream>>>(acc, nsdf, csdf, unfin, listA, cnt + 1 + it, R, it > 0);
        evalL(gA, listA, cnt + 1 + it, 0, acc, nsdf, 1, listB, cnt + 11 + it, 0);
        evalL(gA, listB, cnt + 11 + it, 0, acc, nsdf, 0, nullptr, nullptr, 0);
    }

    k_post<<<gR, 256, 0, stream>>>(cam, rays, acc, nsdf, unfin, listS, cnt + 21,
                                   smin, smax, out, R);
    evalL(gS, listS, cnt + 21, 1, nullptr, sdfv, 0, nullptr, nullptr, 0);
    k_argmin<<<gR, 256, 0, stream>>>(sdfv, smin, smax, listS, cnt + 21,
                                     zlow, zhigh, slow, shigh, zpred, sdorig, netsurf, R);
    for (int i = 0; i < 8; ++i)
        evalL(gC, listS, cnt + 21, 0, zpred, nullptr, 0, nullptr, nullptr, 1);
    k_final<<<gR, 256, 0, stream>>>(cam, rays, listS, cnt + 21, netsurf, zpred, sdorig, out, R);
}

// Round 4
// 901.767 us; speedup vs baseline: 1.8150x; 1.6809x over previous
//
#include <hip/hip_runtime.h>
#include <math.h>

#define HD 256      // hidden dim
#define TPTS 32     // points per block (big/sampler path)
#define TPS 8       // points per block (small/latency path)
#define KT 32       // k-tile for W2 staging (big path)
#define NSTEPS 100
#define TH 5e-5f

__device__ __forceinline__ float secant_pred(float sl, float sh, float zl, float zh) {
    float den = sh - sl;
    den = (fabsf(den) > 1e-12f) ? den : 1e-12f;
    return -sl * (zh - zl) / den + zl;
}

// ---------------------------------------------------------------------------
// BIG path (sampler only): 32 points/block, W2 staged through LDS.
// Proven at ~96% of fp32 roofline for large point counts.
// ---------------------------------------------------------------------------
__global__ __launch_bounds__(256, 2) void eval_kernel(
    const float* __restrict__ cam, const float* __restrict__ rays, int R,
    const int* __restrict__ list, const int* __restrict__ cnt,
    const float* __restrict__ smin, const float* __restrict__ smax,
    float* __restrict__ out,
    const float* __restrict__ W1, const float* __restrict__ b1,
    const float* __restrict__ W2, const float* __restrict__ b2,
    const float* __restrict__ W3, const float* __restrict__ b3)
{
    __shared__ float h1[TPTS][HD];     // 32 KB
    __shared__ float w2t[KT][HD];      // 32 KB
    __shared__ float ptsS[TPTS][4];
    __shared__ int   pidS[TPTS];
    __shared__ float redw[4][TPTS / 2];

    const int tid = threadIdx.x;
    const int v0  = blockIdx.x * TPTS;
    const int n   = cnt[0];
    const int tot = n * NSTEPS;
    if (v0 >= tot) return;   // block-uniform early exit

    if (tid < TPTS) {
        int v = v0 + tid;
        int pid = -1;
        float px = 0.f, py = 0.f, pz = 0.f;
        if (v < tot) {
            int li = v / NSTEPS;
            int st = v - li * NSTEPS;
            int r = list[li];
            float a = smin[r], b = smax[r];
            float t = a + (b - a) * ((float)st / (float)(NSTEPS - 1));
            pid = r * NSTEPS + st;
            px = cam[3 * r + 0] + t * rays[3 * r + 0];
            py = cam[3 * r + 1] + t * rays[3 * r + 1];
            pz = cam[3 * r + 2] + t * rays[3 * r + 2];
        }
        ptsS[tid][0] = px; ptsS[tid][1] = py; ptsS[tid][2] = pz;
        pidS[tid] = pid;
    }
    __syncthreads();

    const int half  = tid >> 7;          // 0 or 1
    const int j0    = tid & 127;
    const int j1    = j0 + 128;
    const int pbase = half * (TPTS / 2); // 0 or 16

    // ---- layer 1 ----
    {
        float wa0 = W1[j0], wa1 = W1[HD + j0], wa2 = W1[2 * HD + j0], ba = b1[j0];
        float wb0 = W1[j1], wb1 = W1[HD + j1], wb2 = W1[2 * HD + j1], bb = b1[j1];
#pragma unroll
        for (int i = 0; i < TPTS / 2; ++i) {
            int p = pbase + i;
            float x = ptsS[p][0], y = ptsS[p][1], z = ptsS[p][2];
            h1[p][j0] = tanhf(ba + x * wa0 + y * wa1 + z * wa2);
            h1[p][j1] = tanhf(bb + x * wb0 + y * wb1 + z * wb2);
        }
    }
    __syncthreads();

    // ---- layer 2 (k-tiled through LDS) ----
    float acca[TPTS / 2], accb[TPTS / 2];
    {
        float b2a = b2[j0], b2b = b2[j1];
#pragma unroll
        for (int i = 0; i < TPTS / 2; ++i) { acca[i] = b2a; accb[i] = b2b; }
    }
    for (int k0 = 0; k0 < HD; k0 += KT) {
        for (int idx = tid; idx < KT * HD; idx += 256)
            ((float*)w2t)[idx] = W2[k0 * HD + idx];
        __syncthreads();
#pragma unroll
        for (int kk = 0; kk < KT; kk += 4) {
            float wa0 = w2t[kk][j0], wa1 = w2t[kk + 1][j0], wa2 = w2t[kk + 2][j0], wa3 = w2t[kk + 3][j0];
            float wb0 = w2t[kk][j1], wb1 = w2t[kk + 1][j1], wb2 = w2t[kk + 2][j1], wb3 = w2t[kk + 3][j1];
#pragma unroll
            for (int i = 0; i < TPTS / 2; ++i) {
                const float4 h4 = *(const float4*)&h1[pbase + i][k0 + kk];
                acca[i] = fmaf(h4.w, wa3, fmaf(h4.z, wa2, fmaf(h4.y, wa1, fmaf(h4.x, wa0, acca[i]))));
                accb[i] = fmaf(h4.w, wb3, fmaf(h4.z, wb2, fmaf(h4.y, wb1, fmaf(h4.x, wb0, accb[i]))));
            }
        }
        __syncthreads();
    }

    // ---- layer 3 + reduction ----
    {
        float w3a = W3[j0], w3b = W3[j1];
        float sum[TPTS / 2];
#pragma unroll
        for (int i = 0; i < TPTS / 2; ++i)
            sum[i] = tanhf(acca[i]) * w3a + tanhf(accb[i]) * w3b;
#pragma unroll
        for (int off = 32; off > 0; off >>= 1)
#pragma unroll
            for (int i = 0; i < TPTS / 2; ++i)
                sum[i] += __shfl_down(sum[i], off);
        int wave = tid >> 6, lane = tid & 63;
        if (lane == 0)
#pragma unroll
            for (int i = 0; i < TPTS / 2; ++i) redw[wave][i] = sum[i];
    }
    __syncthreads();
    if (tid < TPTS) {
        int pid = pidS[tid];
        if (pid >= 0) {
            int p = tid;
            int w0 = (p < TPTS / 2) ? 0 : 2;
            int ii = p & (TPTS / 2 - 1);
            float tot3 = redw[w0][ii] + redw[w0 + 1][ii];
            float x = ptsS[p][0], y = ptsS[p][1], z = ptsS[p][2];
            float base = sqrtf(x * x + y * y + z * z + 1e-12f) - 0.6f;
            out[pid] = base + 0.05f * (tot3 + b3[0]);
        }
    }
}

// ---------------------------------------------------------------------------
// SMALL path: 8 points/block, 256 threads; thread j owns column j for all 8
// points. W2 read directly from global (L2/L3-resident, coalesced); h1 via
// LDS broadcast. ~8.5 KB LDS -> occupancy is block-count bound (P/8 blocks).
//  doLS: epilogue line-search update + append np points to listB/cntB.
//  doSec: epilogue secant bracket update in-place.
// ---------------------------------------------------------------------------
__global__ __launch_bounds__(256, 4) void eval_small(
    const float* __restrict__ cam, const float* __restrict__ rays, int R,
    const int* __restrict__ list, const int* __restrict__ cnt,
    const float* __restrict__ tarr,
    float* __restrict__ out,
    int doLS, float* __restrict__ accLS, const float* __restrict__ csdf,
    int* __restrict__ listB, int* __restrict__ cntB,
    int doSec, float* __restrict__ zlow, float* __restrict__ zhigh,
    float* __restrict__ slow, float* __restrict__ shigh, float* __restrict__ zpred,
    const float* __restrict__ W1, const float* __restrict__ b1,
    const float* __restrict__ W2, const float* __restrict__ b2,
    const float* __restrict__ W3, const float* __restrict__ b3)
{
    __shared__ float h1s[TPS][HD];     // 8 KB
    __shared__ float pS[TPS][4];
    __shared__ int   pidS[TPS];
    __shared__ float red[4][TPS];

    const int tid = threadIdx.x;
    const int v0  = blockIdx.x * TPS;
    const int n   = cnt[0];
    if (v0 >= n) return;    // block-uniform early exit

    if (tid < TPS) {
        int v = v0 + tid;
        int pid = -1;
        float px = 0.f, py = 0.f, pz = 0.f;
        if (v < n) {
            int p = list[v];
            int r = (p < R) ? p : p - R;
            float t = tarr[p];
            pid = p;
            px = cam[3 * r + 0] + t * rays[3 * r + 0];
            py = cam[3 * r + 1] + t * rays[3 * r + 1];
            pz = cam[3 * r + 2] + t * rays[3 * r + 2];
        }
        pS[tid][0] = px; pS[tid][1] = py; pS[tid][2] = pz;
        pidS[tid] = pid;
    }
    __syncthreads();

    const int j = tid;   // column 0..255

    // ---- layer 1: h1s[p][j] = tanh(b1[j] + p . W1[:,j]) ----
    {
        float w0 = W1[j], w1 = W1[HD + j], w2 = W1[2 * HD + j], bb = b1[j];
#pragma unroll
        for (int p = 0; p < TPS; ++p) {
            float x = pS[p][0], y = pS[p][1], z = pS[p][2];
            h1s[p][j] = tanhf(bb + x * w0 + y * w1 + z * w2);
        }
    }
    __syncthreads();

    // ---- layer 2: acc[p] = b2[j] + sum_k h1s[p][k] * W2[k][j] ----
    float acc[TPS];
    {
        float b = b2[j];
#pragma unroll
        for (int p = 0; p < TPS; ++p) acc[p] = b;
    }
#pragma unroll 4
    for (int k0 = 0; k0 < HD; k0 += 4) {
        float w0 = W2[(k0 + 0) * HD + j];
        float w1 = W2[(k0 + 1) * HD + j];
        float w2 = W2[(k0 + 2) * HD + j];
        float w3 = W2[(k0 + 3) * HD + j];
#pragma unroll
        for (int p = 0; p < TPS; ++p) {
            const float4 h4 = *(const float4*)&h1s[p][k0];
            acc[p] = fmaf(h4.w, w3, fmaf(h4.z, w2, fmaf(h4.y, w1, fmaf(h4.x, w0, acc[p]))));
        }
    }

    // ---- layer 3 + block reduction ----
    {
        float w3c = W3[j];
        float sum[TPS];
#pragma unroll
        for (int p = 0; p < TPS; ++p)
            sum[p] = tanhf(acc[p]) * w3c;
#pragma unroll
        for (int off = 32; off > 0; off >>= 1)
#pragma unroll
            for (int p = 0; p < TPS; ++p)
                sum[p] += __shfl_down(sum[p], off);
        int wave = tid >> 6, lane = tid & 63;
        if (lane == 0)
#pragma unroll
            for (int p = 0; p < TPS; ++p) red[wave][p] = sum[p];
    }
    __syncthreads();

    if (tid < TPS) {
        int pid = pidS[tid];
        if (pid >= 0) {
            float tot3 = red[0][tid] + red[1][tid] + red[2][tid] + red[3][tid];
            float x = pS[tid][0], y = pS[tid][1], z = pS[tid][2];
            float base = sqrtf(x * x + y * y + z * z + 1e-12f) - 0.6f;
            float s = base + 0.05f * (tot3 + b3[0]);
            if (doSec) {
                int r = pid;  // secant list stores ray ids
                float zl = zlow[r], zh = zhigh[r], sl = slow[r], sh = shigh[r], zp = zpred[r];
                if (s > 0.0f) { zl = zp; sl = s; }
                if (s < 0.0f) { zh = zp; sh = s; }
                zlow[r] = zl; zhigh[r] = zh; slow[r] = sl; shigh[r] = sh;
                zpred[r] = secant_pred(sl, sh, zl, zh);
            } else {
                out[pid] = s;
                if (doLS && s < 0.0f) {
                    float sgn = (pid < R) ? -0.5f : 0.5f;   // step=(1-0.5)/2^0=0.5
                    accLS[pid] += sgn * csdf[pid];
                    int ix = atomicAdd(cntB, 1);
                    listB[ix] = pid;
                }
            }
        }
    }
}

// ---------------------------------------------------------------------------
__global__ void k_zero(int* __restrict__ c) {
    if (threadIdx.x < 32) c[threadIdx.x] = 0;
}

__global__ void k_init(const float* __restrict__ cam, const float* __restrict__ rays,
                       float* __restrict__ acc, int* __restrict__ unfin,
                       int* __restrict__ listA, int* __restrict__ cntA, int R)
{
    int r = blockIdx.x * blockDim.x + threadIdx.x;
    if (r >= R) return;
    float cx = cam[3 * r], cy = cam[3 * r + 1], cz = cam[3 * r + 2];
    float dx = rays[3 * r], dy = rays[3 * r + 1], dz = rays[3 * r + 2];
    float rcd = cx * dx + cy * dy + cz * dz;
    float cc = cx * cx + cy * cy + cz * cz;
    float under = rcd * rcd - (cc - 1.0f);
    int mi = under > 0.0f;
    float sq = sqrtf(mi ? under : 1.0f);
    float a0 = mi ? fmaxf(-sq - rcd, 0.0f) : 0.0f;
    float a1 = mi ? fmaxf(sq - rcd, 0.0f) : 0.0f;
    acc[r] = a0; acc[R + r] = a1;
    unfin[r] = mi; unfin[R + r] = mi;
    if (mi) {
        int ix = atomicAdd(cntA, 2);
        listA[ix] = r; listA[ix + 1] = R + r;
    }
}

__global__ void k_step(float* __restrict__ acc, const float* __restrict__ nsdf,
                       float* __restrict__ csdf, int* __restrict__ unfin,
                       int* __restrict__ listA, int* __restrict__ cntA, int R, int dom)
{
    int r = blockIdx.x * blockDim.x + threadIdx.x;
    if (r >= R) return;
    float as = acc[r], ae = acc[R + r];
    int us = unfin[r], ue = unfin[R + r];
    if (dom) { int d = as < ae; us = us && d; ue = ue && d; }
    float cs = us ? nsdf[r] : 0.0f;     cs = (cs <= TH) ? 0.0f : cs;
    float ce = ue ? nsdf[R + r] : 0.0f; ce = (ce <= TH) ? 0.0f : ce;
    us = us && (cs > TH); ue = ue && (ce > TH);
    acc[r] = as + cs; acc[R + r] = ae - ce;
    csdf[r] = cs; csdf[R + r] = ce;
    unfin[r] = us; unfin[R + r] = ue;
    if (us) listA[atomicAdd(cntA, 1)] = r;
    if (ue) listA[atomicAdd(cntA, 1)] = R + r;
}

__global__ void k_post(const float* __restrict__ cam, const float* __restrict__ rays,
                       const float* __restrict__ acc, const float* __restrict__ nsdf,
                       const int* __restrict__ unfin,
                       int* __restrict__ listS, int* __restrict__ cntS,
                       float* __restrict__ smin, float* __restrict__ smax,
                       float* __restrict__ out, int R)
{
    int r = blockIdx.x * blockDim.x + threadIdx.x;
    if (r >= R) return;
    float as = acc[r], ae = acc[R + r];
    int us = unfin[r];
    int d = as < ae;
    us = us && d;                               // loop-end domain check
    float cs = us ? nsdf[r] : 0.0f;
    cs = (cs <= TH) ? 0.0f : cs;
    us = us && (cs > TH);                       // final mask refinement
    smin[r] = as;
    smax[r] = ae;
    if (us) listS[atomicAdd(cntS, 1)] = r;
    // preliminary outputs (sampler path overwrites where sampler_mask)
    out[3 * r + 0] = cam[3 * r + 0] + as * rays[3 * r + 0];
    out[3 * r + 1] = cam[3 * r + 1] + as * rays[3 * r + 1];
    out[3 * r + 2] = cam[3 * r + 2] + as * rays[3 * r + 2];
    out[3 * R + r] = d ? 1.0f : 0.0f;
    out[4 * R + r] = as;
}

__global__ void k_argmin(const float* __restrict__ sdfv, const float* __restrict__ smin,
                         const float* __restrict__ smax,
                         const int* __restrict__ listS, const int* __restrict__ cntS,
                         float* __restrict__ zlow, float* __restrict__ zhigh,
                         float* __restrict__ slow, float* __restrict__ shigh,
                         float* __restrict__ zpred, float* __restrict__ sdorig,
                         int* __restrict__ netsurf, int R)
{
    int j = blockIdx.x * blockDim.x + threadIdx.x;
    if (j >= cntS[0]) return;
    int r = listS[j];
    float a = smin[r], b = smax[r];
    float d = b - a;
    float best = 1e30f; int ind = 0;
    for (int i = 0; i < NSTEPS; ++i) {
        float sv = sdfv[r * NSTEPS + i];
        float sgn = (float)((sv > 0.0f) - (sv < 0.0f));
        float tmp = sgn * (float)(NSTEPS - i);
        if (tmp < best) { best = tmp; ind = i; }
    }
    float zh = a + d * ((float)ind / (float)(NSTEPS - 1));
    float sh = sdfv[r * NSTEPS + ind];
    int il = (ind + NSTEPS - 1) % NSTEPS;
    float zl = a + d * ((float)il / (float)(NSTEPS - 1));
    float sl = sdfv[r * NSTEPS + il];
    netsurf[r] = (sh < 0.0f);
    sdorig[r] = zh;
    zlow[r] = zl; zhigh[r] = zh; slow[r] = sl; shigh[r] = sh;
    zpred[r] = secant_pred(sl, sh, zl, zh);
}

__global__ void k_final(const float* __restrict__ cam, const float* __restrict__ rays,
                        const int* __restrict__ listS, const int* __restrict__ cntS,
                        const int* __restrict__ netsurf,
                        const float* __restrict__ zpred, const float* __restrict__ sdorig,
                        float* __restrict__ out, int R)
{
    int j = blockIdx.x * blockDim.x + threadIdx.x;
    if (j >= cntS[0]) return;
    int r = listS[j];
    int ns = netsurf[r];
    float dist = ns ? zpred[r] : sdorig[r];
    out[3 * r + 0] = cam[3 * r + 0] + dist * rays[3 * r + 0];
    out[3 * r + 1] = cam[3 * r + 1] + dist * rays[3 * r + 1];
    out[3 * r + 2] = cam[3 * r + 2] + dist * rays[3 * r + 2];
    out[3 * R + r] = ns ? 1.0f : 0.0f;
    out[4 * R + r] = dist;
}

// ---------------------------------------------------------------------------
extern "C" void kernel_launch(void* const* d_in, const int* in_sizes, int n_in,
                              void* d_out, int out_size, void* d_ws, size_t ws_size,
                              hipStream_t stream)
{
    const float* cam  = (const float*)d_in[0];
    const float* rays = (const float*)d_in[1];
    const float* W1   = (const float*)d_in[3];
    const float* b1   = (const float*)d_in[4];
    const float* W2   = (const float*)d_in[5];
    const float* b2   = (const float*)d_in[6];
    const float* W3   = (const float*)d_in[7];
    const float* b3   = (const float*)d_in[8];
    const int R = in_sizes[0] / 3;
    float* out = (float*)d_out;

    float* f = (float*)d_ws;
    float* acc    = f; f += 2 * R;
    float* nsdf   = f; f += 2 * R;
    float* csdf   = f; f += 2 * R;
    float* smin   = f; f += R;
    float* smax   = f; f += R;
    float* zlow   = f; f += R;
    float* zhigh  = f; f += R;
    float* slow   = f; f += R;
    float* shigh  = f; f += R;
    float* zpred  = f; f += R;
    float* sdorig = f; f += R;
    float* sdfv   = f; f += R * NSTEPS;
    int* unfin    = (int*)f; f += 2 * R;
    int* listA    = (int*)f; f += 2 * R;
    int* listB    = (int*)f; f += 2 * R;
    int* listS    = (int*)f; f += R;
    int* netsurf  = (int*)f; f += R;
    int* cnt      = (int*)f; f += 32;
    // counter slots: 0=init listA; 1+it = k_step listA; 11+it = listB; 21 = listS

    const int gR   = (R + 255) / 256;
    const int gAs  = (2 * R + TPS - 1) / TPS;          // 1024 blocks (small path)
    const int gCs  = (R + TPS - 1) / TPS;              // 512 blocks (secant, small path)
    const int gS   = (R * NSTEPS + TPTS - 1) / TPTS;   // 12800 blocks (sampler, big path)

    auto evalS = [&](int blocks, const int* list, const int* c,
                     const float* tarr, float* o,
                     int doLS, int* lB, int* cB, int doSec) {
        hipLaunchKernelGGL(eval_small, dim3(blocks), dim3(256), 0, stream,
                           cam, rays, R, list, c, tarr, o,
                           doLS, acc, csdf, lB, cB,
                           doSec, zlow, zhigh, slow, shigh, zpred,
                           W1, b1, W2, b2, W3, b3);
    };

    k_zero<<<1, 64, 0, stream>>>(cnt);
    k_init<<<gR, 256, 0, stream>>>(cam, rays, acc, unfin, listA, cnt + 0, R);
    evalS(gAs, listA, cnt + 0, acc, nsdf, 0, nullptr, nullptr, 0);

    for (int it = 0; it < 10; ++it) {
        k_step<<<gR, 256, 0, stream>>>(acc, nsdf, csdf, unfin, listA, cnt + 1 + it, R, it > 0);
        evalS(gAs, listA, cnt + 1 + it, acc, nsdf, 1, listB, cnt + 11 + it, 0);
        evalS(gAs, listB, cnt + 11 + it, acc, nsdf, 0, nullptr, nullptr, 0);
    }

    k_post<<<gR, 256, 0, stream>>>(cam, rays, acc, nsdf, unfin, listS, cnt + 21,
                                   smin, smax, out, R);
    hipLaunchKernelGGL(eval_kernel, dim3(gS), dim3(256), 0, stream,
                       cam, rays, R, listS, cnt + 21, smin, smax, sdfv,
                       W1, b1, W2, b2, W3, b3);
    k_argmin<<<gR, 256, 0, stream>>>(sdfv, smin, smax, listS, cnt + 21,
                                     zlow, zhigh, slow, shigh, zpred, sdorig, netsurf, R);
    for (int i = 0; i < 8; ++i)
        evalS(gCs, listS, cnt + 21, zpred, nullptr, 0, nullptr, nullptr, 1);
    k_final<<<gR, 256, 0, stream>>>(cam, rays, listS, cnt + 21, netsurf, zpred, sdorig, out, R);
}